// Round 6
// baseline (347.386 us; speedup 1.0000x reference)
//
#include <hip/hip_runtime.h>
#include <stdint.h>

constexpr int B_ = 64, N_ = 2048, D_ = 256, H_ = 64;
constexpr int M_ = B_ * N_;           // 131072 rows
constexpr int TOPK_ = 204, TOP5_ = 102;
constexpr float NEGINF_ = -1e30f;

// out layout (floats)
constexpr int OUT_BAG  = 0;                      // 64*512
constexpr int OUT_ATTN = 32768;                  // 64*3*2048
constexpr int OUT_AVG  = OUT_ATTN + 393216;      // 425984
constexpr int OUT_TOPK = OUT_AVG + 131072;       // 557056
constexpr int OUT_ENT  = OUT_TOPK + 131072;      // 688128
constexpr int OUT_EFF  = OUT_ENT + 64;           // 688192
constexpr int OUT_T5   = OUT_EFF + 64;           // 688256

// ws layout (floats)
constexpr int WS_TK    = 0;                      // 131072
constexpr int WS_SC    = 131072;                 // [s*64+b][n] : 393216
constexpr int WS_STATS = WS_SC + 393216;         // 524288 : [b]=valid, [64+b]=topk
constexpr int WS_PART  = WS_STATS + 128;         // 524416 : [b*8+ch][5][256]
constexpr int WS_BFRAG = WS_PART + 655360;       // 1179776 : 131072 bf16
constexpr int WS_X1    = WS_BFRAG + 32768;       // 1212544 : [b][512]
constexpr int WS_G     = WS_X1 + 32768;          // 1245312 : [b][512]

typedef short  bf16x8 __attribute__((ext_vector_type(8)));
typedef float  f32x4  __attribute__((ext_vector_type(4)));

__device__ __forceinline__ short cvt_bf16(float f) {
    unsigned u = __float_as_uint(f);
    unsigned r = (u + 0x7FFFu + ((u >> 16) & 1u)) >> 16;
    return (short)r;
}
__device__ __forceinline__ unsigned pack_bf16x2(float a, float b) {
    return (unsigned)(unsigned short)cvt_bf16(a) | ((unsigned)(unsigned short)cvt_bf16(b) << 16);
}
__device__ __forceinline__ float tanh_fast(float x) {
    float e = __expf(2.0f * x);
    return 1.0f - 2.0f / (e + 1.0f);
}
__device__ __forceinline__ unsigned flip_f32(float f) {
    unsigned u = __float_as_uint(f);
    return (u & 0x80000000u) ? ~u : (u | 0x80000000u);
}
__device__ __forceinline__ float unflip_f32(unsigned u) {
    unsigned b = (u & 0x80000000u) ? (u & 0x7FFFFFFFu) : ~u;
    return __uint_as_float(b);
}

__device__ __forceinline__ float block_sum256(float v, volatile float* red, int t) {
    #pragma unroll
    for (int off = 32; off; off >>= 1) v += __shfl_xor(v, off, 64);
    __syncthreads();
    if ((t & 63) == 0) red[t >> 6] = v;
    __syncthreads();
    return red[0] + red[1] + red[2] + red[3];
}
__device__ __forceinline__ float block_max256(float v, volatile float* red, int t) {
    #pragma unroll
    for (int off = 32; off; off >>= 1) v = fmaxf(v, __shfl_xor(v, off, 64));
    __syncthreads();
    if ((t & 63) == 0) red[t >> 6] = v;
    __syncthreads();
    return fmaxf(fmaxf(red[0], red[1]), fmaxf(red[2], red[3]));
}

// radix-select: key of the k-th largest among key[0..n) (flipped-float order).
__device__ unsigned radix_kth(const unsigned* key, int n, int k,
                              unsigned* hist, int* sdig, int t, int* rem_out)
{
    unsigned prefix = 0;
    int kk = k;
    #pragma unroll
    for (int pass = 0; pass < 4; ++pass) {
        const int shift = 24 - 8 * pass;
        const unsigned hi_mask = (pass == 0) ? 0u : (0xFFFFFFFFu << (shift + 8));
        hist[t] = 0;
        __syncthreads();
        for (int i = t; i < n; i += 256) {
            unsigned u = key[i];
            if ((u & hi_mask) == (prefix & hi_mask))
                atomicAdd(&hist[(u >> shift) & 0xFFu], 1u);
        }
        __syncthreads();
        for (int s = 1; s < 256; s <<= 1) {
            unsigned v = (t + s < 256) ? hist[t + s] : 0u;
            __syncthreads();
            hist[t] += v;
            __syncthreads();
        }
        if (t == 0) *sdig = 0;
        __syncthreads();
        if ((int)hist[t] >= kk) atomicMax(sdig, t);
        __syncthreads();
        const int dig = *sdig;
        if (dig < 255) kk -= (int)hist[dig + 1];
        prefix |= (unsigned)dig << shift;
        __syncthreads();
    }
    *rem_out = kk;
    return prefix;
}

// ---------------- K0: pack W = [Ws1 | Wa1_0 | Wa1_1 | Wa1_2] into bf16 B-fragments ----
__global__ __launch_bounds__(256)
void k_prep(const float* __restrict__ Ws1, const float* __restrict__ Wa1,
            short* __restrict__ wsB)
{
    const int id = blockIdx.x * 256 + threadIdx.x;   // (c,ct,lane)
    if (id >= 16384) return;
    const int lane = id & 63, ct = (id >> 6) & 15, c = id >> 10;
    const int col = ct * 16 + (lane & 15);
    const int kb  = c * 32 + ((lane >> 4) << 3);
    bf16x8 v;
    #pragma unroll
    for (int j = 0; j < 8; ++j) {
        const int k = kb + j;
        float w = (col < 64) ? Ws1[(size_t)k * H_ + col]
                             : Wa1[(((size_t)(col >> 6) - 1) * D_ + k) * H_ + (col & 63)];
        v[j] = cvt_bf16(w);
    }
    *(bf16x8*)(wsB + (size_t)id * 8) = v;
}

// ---------------- K1: MFMA scorer — X in LDS (once), B in registers per wave ------
// Each wave owns one 64-col set s (s=0 scorer relu path, s=1..3 tanh branches);
// epilogue second-layer dot is wave-private.
__global__ __launch_bounds__(256)
void k_scores(const float* __restrict__ inst, const float* __restrict__ mask,
              const short* __restrict__ wsB,
              const float* __restrict__ bs1, const float* __restrict__ Ws2,
              const float* __restrict__ bs2,
              const float* __restrict__ ba1, const float* __restrict__ Wa2,
              const float* __restrict__ ba2,
              float* __restrict__ ws)
{
    __shared__ unsigned xas[8192];               // 32 KB: X tile bf16, A-frag layout
    const int t = threadIdx.x;
    const int s = t >> 6, l = t & 63;            // wave s = col-set
    const int li = l & 15, qu = l >> 4;
    const int row0 = blockIdx.x * 64;

    // ---- stage X tile (fp32 -> bf16, A-fragment layout), perfectly coalesced ----
    {
        const float4* src = (const float4*)(inst + (size_t)row0 * D_);
        #pragma unroll
        for (int i = 0; i < 16; ++i) {
            const int f = i * 256 + t;           // float4 index in 64x256 tile
            const int row = f >> 6, k4 = f & 63; // k = k4*4
            float4 x = src[f];
            // frag coords: c = k>>5 = k4>>3, rg = (k>>3)&3 = (k4>>1)&3, j0 = (k4&1)*4
            const int base = ((k4 >> 3) * 256) + ((row >> 4) * 64) + (((k4 >> 1) & 3) * 16) + (row & 15);
            const int ui = base * 4 + (k4 & 1) * 2;
            xas[ui]     = pack_bf16x2(x.x, x.y);
            xas[ui + 1] = pack_bf16x2(x.z, x.w);
        }
    }
    __syncthreads();

    f32x4 acc[4][4];                             // [rt][ct']
    #pragma unroll
    for (int rt = 0; rt < 4; ++rt)
        #pragma unroll
        for (int c4 = 0; c4 < 4; ++c4) acc[rt][c4] = (f32x4){0.f, 0.f, 0.f, 0.f};

    const bf16x8* Bg = (const bf16x8*)wsB;       // [(c*16+ct)*64 + l]
    bf16x8 bcur[4], bnxt[4];
    #pragma unroll
    for (int c4 = 0; c4 < 4; ++c4) bcur[c4] = Bg[(0 * 16 + s * 4 + c4) * 64 + l];

    #pragma unroll
    for (int c = 0; c < 8; ++c) {
        if (c < 7) {
            #pragma unroll
            for (int c4 = 0; c4 < 4; ++c4) bnxt[c4] = Bg[((c + 1) * 16 + s * 4 + c4) * 64 + l];
        }
        #pragma unroll
        for (int rt = 0; rt < 4; ++rt) {
            bf16x8 a = ((const bf16x8*)xas)[(c * 4 + rt) * 64 + l];
            #pragma unroll
            for (int c4 = 0; c4 < 4; ++c4)
                acc[rt][c4] = __builtin_amdgcn_mfma_f32_16x16x32_bf16(a, bcur[c4], acc[rt][c4], 0, 0, 0);
        }
        #pragma unroll
        for (int c4 = 0; c4 < 4; ++c4) bcur[c4] = bnxt[c4];
    }

    // ---- epilogue: bias + act + dot(W2) over this wave's 64 cols ----
    float bias[4], w2v[4];
    #pragma unroll
    for (int c4 = 0; c4 < 4; ++c4) {
        const int h = c4 * 16 + li;              // 0..63 within set
        if (s == 0) { bias[c4] = bs1[h];                w2v[c4] = Ws2[h]; }
        else        { bias[c4] = ba1[(s - 1) * H_ + h]; w2v[c4] = Wa2[(s - 1) * H_ + h]; }
    }
    const float b2 = (s == 0) ? bs2[0] : ba2[s - 1];
    float* dst = (s == 0) ? (ws + WS_TK) : (ws + WS_SC + (size_t)(s - 1) * M_);

    #pragma unroll
    for (int rt = 0; rt < 4; ++rt) {
        #pragma unroll
        for (int i = 0; i < 4; ++i) {
            float p = 0.0f;
            #pragma unroll
            for (int c4 = 0; c4 < 4; ++c4) {
                float v = acc[rt][c4][i] + bias[c4];
                p += (s == 0 ? fmaxf(v, 0.0f) : tanh_fast(v)) * w2v[c4];
            }
            #pragma unroll
            for (int off = 1; off < 16; off <<= 1) p += __shfl_xor(p, off, 64);
            if (li == 0) {
                const int gr = row0 + rt * 16 + qu * 4 + i;
                dst[gr] = (mask[gr] == 0.0f) ? NEGINF_ : (p + b2);
            }
        }
    }
}

// ---------------- K2: per-batch fused top-k + softmax x3 + diagnostics ----------
__global__ __launch_bounds__(256)
void k_batch(const float* __restrict__ ws_tk, const float* __restrict__ ws_sc,
             const float* __restrict__ mask,
             float* __restrict__ out_topk, float* __restrict__ ws_stats,
             float* __restrict__ out_attn, float* __restrict__ out_avg,
             float* __restrict__ out_ent, float* __restrict__ out_eff,
             float* __restrict__ out_t5)
{
    __shared__ float attn_s[3][N_];              // 24 KB
    __shared__ unsigned ukey[N_];                // 8 KB
    __shared__ unsigned hist[256];
    __shared__ int sdig, tie_cnt;
    __shared__ float red[4];
    const int b = blockIdx.x, t = threadIdx.x;

    // ---- phase 1: top-204 on scorer output ----
    float vsum = 0.0f;
    for (int i = t; i < N_; i += 256) {
        ukey[i] = flip_f32(ws_tk[b * N_ + i]);
        vsum += mask[b * N_ + i];
        out_topk[b * N_ + i] = 0.0f;
    }
    float vs = block_sum256(vsum, red, t);
    if (t == 0) { ws_stats[b] = vs; tie_cnt = 0; }
    __syncthreads();
    int rem;
    unsigned T = radix_kth(ukey, N_, TOPK_, hist, &sdig, t, &rem);
    float csum = 0.0f;
    for (int i = t; i < N_; i += 256) {
        const unsigned u = ukey[i];
        bool take = (u > T);
        if (!take && u == T) take = (atomicAdd(&tie_cnt, 1) < rem);
        if (take) {
            out_topk[b * N_ + i] = 1.0f;
            csum += mask[b * N_ + i];
        }
    }
    float cs = block_sum256(csum, red, t);
    if (t == 0) ws_stats[64 + b] = cs;

    // ---- phase 2: softmax per branch (keep in LDS, also write out) ----
    for (int s = 0; s < 3; ++s) {
        const float* src = ws_sc + ((size_t)s * B_ + b) * N_;
        float fv[8];
        float mx = -3.4e38f;
        #pragma unroll
        for (int m = 0; m < 8; ++m) { fv[m] = src[t + 256 * m]; mx = fmaxf(mx, fv[m]); }
        float bm = block_max256(mx, red, t);
        float sm = 0.0f;
        #pragma unroll
        for (int m = 0; m < 8; ++m) { fv[m] = expf(fv[m] - bm); sm += fv[m]; }
        float tot = block_sum256(sm, red, t);
        float inv = 1.0f / tot;
        float* dst = out_attn + ((size_t)b * 3 + s) * N_;
        #pragma unroll
        for (int m = 0; m < 8; ++m) {
            float a = fv[m] * inv;
            attn_s[s][t + 256 * m] = a;
            dst[t + 256 * m] = a;
        }
    }
    __syncthreads();

    // ---- phase 3: diagnostics ----
    float esum = 0.0f, qsum = 0.0f;
    for (int i = t; i < N_; i += 256) {
        float a = (attn_s[0][i] + attn_s[1][i] + attn_s[2][i]) * (1.0f / 3.0f);
        out_avg[b * N_ + i] = a;
        esum -= a * logf(a + 1e-8f);
        qsum += a * a;
        ukey[i] = flip_f32(a);
    }
    float es = block_sum256(esum, red, t);
    float qs = block_sum256(qsum, red, t);
    if (t == 0) { out_ent[b] = es; out_eff[b] = 1.0f / qs; }
    __syncthreads();
    T = radix_kth(ukey, N_, TOP5_, hist, &sdig, t, &rem);
    float tsum = 0.0f;
    for (int i = t; i < N_; i += 256) {
        const unsigned u = ukey[i];
        if (u > T) tsum += unflip_f32(u);
    }
    float ts = block_sum256(tsum, red, t);
    if (t == 0) out_t5[b] = ts + (float)rem * unflip_f32(T);
}

// ---------------- K4: pooling partials, float4 loads ----------------
__global__ __launch_bounds__(256)
void k_pool(const float* __restrict__ inst, const float* __restrict__ mask,
            const float* __restrict__ out_topk, const float* __restrict__ out_attn,
            float* __restrict__ ws_part)
{
    __shared__ float wgt[5][256];
    __shared__ float4 partial[4][5][64];        // 20 KB
    const int blk = blockIdx.x;                 // b*8 + ch
    const int b = blk >> 3, ch = blk & 7;
    const int n0 = ch * 256;
    const int t = threadIdx.x;
    const int w = t >> 6, l = t & 63;
    {
        float mv = mask[b * N_ + n0 + t];
        wgt[0][t] = mv;
        wgt[1][t] = out_topk[b * N_ + n0 + t] * mv;
        const float* ab = out_attn + (size_t)b * 3 * N_ + n0 + t;
        wgt[2][t] = ab[0];
        wgt[3][t] = ab[N_];
        wgt[4][t] = ab[2 * N_];
    }
    __syncthreads();
    float4 a0 = {0,0,0,0}, a1 = {0,0,0,0}, a2 = {0,0,0,0}, a3 = {0,0,0,0}, a4 = {0,0,0,0};
    const float4* xp = (const float4*)(inst + ((size_t)b * N_ + n0 + w * 64) * D_) + l;
    #pragma unroll 4
    for (int nn = 0; nn < 64; ++nn) {
        float4 x = xp[(size_t)nn * 64];
        float w0 = wgt[0][w * 64 + nn], w1 = wgt[1][w * 64 + nn];
        float w2 = wgt[2][w * 64 + nn], w3 = wgt[3][w * 64 + nn];
        float w4 = wgt[4][w * 64 + nn];
        a0.x = fmaf(x.x, w0, a0.x); a0.y = fmaf(x.y, w0, a0.y);
        a0.z = fmaf(x.z, w0, a0.z); a0.w = fmaf(x.w, w0, a0.w);
        a1.x = fmaf(x.x, w1, a1.x); a1.y = fmaf(x.y, w1, a1.y);
        a1.z = fmaf(x.z, w1, a1.z); a1.w = fmaf(x.w, w1, a1.w);
        a2.x = fmaf(x.x, w2, a2.x); a2.y = fmaf(x.y, w2, a2.y);
        a2.z = fmaf(x.z, w2, a2.z); a2.w = fmaf(x.w, w2, a2.w);
        a3.x = fmaf(x.x, w3, a3.x); a3.y = fmaf(x.y, w3, a3.y);
        a3.z = fmaf(x.z, w3, a3.z); a3.w = fmaf(x.w, w3, a3.w);
        a4.x = fmaf(x.x, w4, a4.x); a4.y = fmaf(x.y, w4, a4.y);
        a4.z = fmaf(x.z, w4, a4.z); a4.w = fmaf(x.w, w4, a4.w);
    }
    partial[w][0][l] = a0; partial[w][1][l] = a1; partial[w][2][l] = a2;
    partial[w][3][l] = a3; partial[w][4][l] = a4;
    __syncthreads();
    for (int idx = t; idx < 320; idx += 256) {
        const int j = idx >> 6, l2 = idx & 63;
        float4 s0 = partial[0][j][l2], s1 = partial[1][j][l2];
        float4 s2 = partial[2][j][l2], s3 = partial[3][j][l2];
        float4 sm;
        sm.x = s0.x + s1.x + s2.x + s3.x;
        sm.y = s0.y + s1.y + s2.y + s3.y;
        sm.z = s0.z + s1.z + s2.z + s3.z;
        sm.w = s0.w + s1.w + s2.w + s3.w;
        *(float4*)(ws_part + (size_t)blk * 1280 + j * 256 + l2 * 4) = sm;
    }
}

// ---------------- K7a: x1 = cat @ Wf1 + bf1 (cat folded in; split-K GEMV) ----------
__global__ __launch_bounds__(256)
void k_fuse1(const float* __restrict__ ws_part, const float* __restrict__ ws_stats,
             const float* __restrict__ Wf1, const float* __restrict__ bf1,
             float* __restrict__ x1)
{
    __shared__ float cl[1280];
    __shared__ float part[256];
    const int blk = blockIdx.x;                 // b*8 + c
    const int b = blk >> 3, c = blk & 7;
    const int t = threadIdx.x;
    const float inv0 = 1.0f / fmaxf(ws_stats[b], 1.0f);
    const float inv1 = 1.0f / fmaxf(ws_stats[64 + b], 1.0f);
    for (int i = t; i < 1280; i += 256) {
        const int j = i >> 8, d = i & 255;
        float s = 0.0f;
        #pragma unroll
        for (int cc = 0; cc < 8; ++cc)
            s += ws_part[((size_t)(b * 8 + cc) * 5 + j) * 256 + d];
        if (j == 0)      s *= inv0;
        else if (j == 1) s *= inv1;
        cl[i] = s;
    }
    __syncthreads();
    const int j = c * 64 + (t & 63);
    const int s = t >> 6;
    float acc = 0.0f;
    const float* wp = Wf1 + (size_t)(s * 320) * 512 + j;
    #pragma unroll 8
    for (int i = 0; i < 320; ++i)
        acc = fmaf(cl[s * 320 + i], wp[(size_t)i * 512], acc);
    part[t] = acc;
    __syncthreads();
    if (t < 64)
        x1[b * 512 + c * 64 + t] =
            part[t] + part[64 + t] + part[128 + t] + part[192 + t] + bf1[c * 64 + t];
}

// ---------------- K7b: LayerNorm + GELU(erf) ----------------
__global__ __launch_bounds__(256)
void k_fuse2(const float* __restrict__ x1, const float* __restrict__ ln_g,
             const float* __restrict__ ln_b, float* __restrict__ g)
{
    __shared__ float red[4];
    const int b = blockIdx.x, t = threadIdx.x;
    float v0 = x1[b * 512 + t], v1 = x1[b * 512 + 256 + t];
    float mu = block_sum256(v0 + v1, red, t) * (1.0f / 512.0f);
    float d0 = v0 - mu, d1 = v1 - mu;
    float var = block_sum256(d0 * d0 + d1 * d1, red, t) * (1.0f / 512.0f);
    float is = 1.0f / sqrtf(var + 1e-5f);
    float y0 = d0 * is * ln_g[t] + ln_b[t];
    float y1 = d1 * is * ln_g[t + 256] + ln_b[t + 256];
    g[b * 512 + t]       = 0.5f * y0 * (1.0f + erff(y0 * 0.70710678118654752440f));
    g[b * 512 + 256 + t] = 0.5f * y1 * (1.0f + erff(y1 * 0.70710678118654752440f));
}

// ---------------- K7c: bag = g @ Wf2 + bf2 ----------------
__global__ __launch_bounds__(256)
void k_fuse3(const float* __restrict__ g, const float* __restrict__ Wf2,
             const float* __restrict__ bf2, float* __restrict__ out_bag)
{
    __shared__ float gl[512];
    __shared__ float part[256];
    const int blk = blockIdx.x;                 // b*8 + c
    const int b = blk >> 3, c = blk & 7;
    const int t = threadIdx.x;
    const int j = c * 64 + (t & 63);
    const int s = t >> 6;
    for (int i = t; i < 512; i += 256) gl[i] = g[b * 512 + i];
    __syncthreads();
    float acc = 0.0f;
    const float* wp = Wf2 + (size_t)(s * 128) * 512 + j;
    #pragma unroll 8
    for (int i = 0; i < 128; ++i)
        acc = fmaf(gl[s * 128 + i], wp[(size_t)i * 512], acc);
    part[t] = acc;
    __syncthreads();
    if (t < 64)
        out_bag[b * 512 + c * 64 + t] =
            part[t] + part[64 + t] + part[128 + t] + part[192 + t] + bf2[c * 64 + t];
}

extern "C" void kernel_launch(void* const* d_in, const int* in_sizes, int n_in,
                              void* d_out, int out_size, void* d_ws, size_t ws_size,
                              hipStream_t stream)
{
    (void)in_sizes; (void)n_in; (void)out_size; (void)ws_size;
    const float* inst = (const float*)d_in[0];
    const float* mask = (const float*)d_in[1];
    const float* Ws1  = (const float*)d_in[2];
    const float* bs1  = (const float*)d_in[3];
    const float* Ws2  = (const float*)d_in[4];
    const float* bs2  = (const float*)d_in[5];
    const float* Wa1  = (const float*)d_in[6];
    const float* ba1  = (const float*)d_in[7];
    const float* Wa2  = (const float*)d_in[8];
    const float* ba2  = (const float*)d_in[9];
    const float* Wf1  = (const float*)d_in[10];
    const float* bf1  = (const float*)d_in[11];
    const float* lng  = (const float*)d_in[12];
    const float* lnb  = (const float*)d_in[13];
    const float* Wf2  = (const float*)d_in[14];
    const float* bf2  = (const float*)d_in[15];

    float* out = (float*)d_out;
    float* ws  = (float*)d_ws;
    short* wsB = (short*)(ws + WS_BFRAG);

    k_prep<<<64, 256, 0, stream>>>(Ws1, Wa1, wsB);
    k_scores<<<M_ / 64, 256, 0, stream>>>(inst, mask, wsB, bs1, Ws2, bs2,
                                          ba1, Wa2, ba2, ws);
    k_batch<<<B_, 256, 0, stream>>>(ws + WS_TK, ws + WS_SC, mask,
                                    out + OUT_TOPK, ws + WS_STATS,
                                    out + OUT_ATTN, out + OUT_AVG,
                                    out + OUT_ENT, out + OUT_EFF, out + OUT_T5);
    k_pool<<<B_ * 8, 256, 0, stream>>>(inst, mask, out + OUT_TOPK, out + OUT_ATTN,
                                       ws + WS_PART);
    k_fuse1<<<B_ * 8, 256, 0, stream>>>(ws + WS_PART, ws + WS_STATS, Wf1, bf1,
                                        ws + WS_X1);
    k_fuse2<<<B_, 256, 0, stream>>>(ws + WS_X1, lng, lnb, ws + WS_G);
    k_fuse3<<<B_ * 8, 256, 0, stream>>>(ws + WS_G, Wf2, bf2, out + OUT_BAG);
}